// Round 12
// baseline (10507.986 us; speedup 1.0000x reference)
//
#include <hip/hip_runtime.h>

#define VV 128
#define HH 1024
#define BB 128
#define TT 512
#define G4 4096
#define BTH ((size_t)BB * TT * HH)
#define HPAR (4 * 64 * 512)   // shorts per h ring entry (256 KB)
#define RING 32

typedef __attribute__((ext_vector_type(8))) short bf16x8;
typedef __attribute__((ext_vector_type(16))) float f32x16;
typedef __attribute__((ext_vector_type(4))) unsigned u32x4;

__device__ __forceinline__ short f2bf(float f) {
  unsigned u = __float_as_uint(f);
  u = (u + 0x7fffu + ((u >> 16) & 1u)) >> 16;
  return (short)u;
}

__device__ __forceinline__ float fsig(float x) {
  x = fminf(fmaxf(x, -30.f), 30.f);
  float e = __expf(-x);
  return 1.f / (1.f + e);
}
__device__ __forceinline__ float ftanh(float x) {
  x = fminf(fmaxf(x, -15.f), 15.f);
  float e = __expf(-2.f * x);
  return (1.f - e) / (1.f + e);
}

__device__ __forceinline__ unsigned eidx(int t) {   // ring entry for h[t], scrambled
  return ((unsigned)(t + 1) * 37u) & (RING - 1);
}

// ---------------- pre-kernels ----------------

// h (L,B,H) -> fragment-stream ring entry 0 (the h[-1] slot, eidx(-1)=0)
__global__ void init_state(const float* __restrict__ h,
                           short* __restrict__ h0dst, short* __restrict__ h1dst) {
  const int n = 2 * HPAR;
  for (int i = blockIdx.x * blockDim.x + threadIdx.x; i < n; i += gridDim.x * blockDim.x) {
    int inner = i & (HPAR - 1);
    int l = i >> 17;
    int e = i & 7, lane = (i >> 3) & 63, kc = (i >> 9) & 63, rb = (i >> 15) & 3;
    int row = rb * 32 + (lane & 31);
    int j = kc * 16 + ((lane >> 5) << 3) + e;
    short hb = f2bf(h[((size_t)l * BB + row) * HH + j]);
    (l ? h1dst : h0dst)[inner] = hb;
  }
}

// Pack weights into per-CU per-kc per-lane MFMA B-fragment streams (bf16).
__global__ void pack_w(const float* __restrict__ Wx0, const float* __restrict__ Wh0,
                       const float* __restrict__ Wx1, const float* __restrict__ Wh1,
                       short* __restrict__ wp0, short* __restrict__ wp1) {
  const int n0 = 128 * 72 * 512;
  const int n1 = 128 * 128 * 512;
  for (int i = blockIdx.x * blockDim.x + threadIdx.x; i < n0 + n1; i += gridDim.x * blockDim.x) {
    if (i < n0) {
      int cu = i / (72 * 512);
      int rem = i - cu * (72 * 512);
      int kc = rem >> 9, le = rem & 511;
      int lane = le >> 3, e = le & 7;
      int k = kc * 16 + ((lane >> 5) << 3) + e;
      int cl = lane & 31;
      int gcol = (cl >> 3) * HH + cu * 8 + (cl & 7);
      float f = (k < VV) ? Wx0[(size_t)k * G4 + gcol] : Wh0[(size_t)(k - VV) * G4 + gcol];
      wp0[i] = f2bf(f);
    } else {
      int j = i - n0;
      int cu = j >> 16;
      int rem = j & 65535;
      int kc = rem >> 9, le = rem & 511;
      int lane = le >> 3, e = le & 7;
      int k = kc * 16 + ((lane >> 5) << 3) + e;
      int cl = lane & 31;
      int gcol = (cl >> 3) * HH + cu * 8 + (cl & 7);
      float f = (k < HH) ? Wx1[(size_t)k * G4 + gcol] : Wh1[(size_t)(k - HH) * G4 + gcol];
      wp1[j] = f2bf(f);
    }
  }
}

__global__ void pack_b(const float* __restrict__ b0, const float* __restrict__ b1,
                       float* __restrict__ bp, unsigned* __restrict__ slots) {
  int i = blockIdx.x * blockDim.x + threadIdx.x;
  if (i < 2 * 128 * 32) {
    int l = i >> 12;
    int cu = (i >> 5) & 127;
    int cc = i & 31;
    const float* b = l ? b1 : b0;
    bp[i] = b[(cc >> 3) * HH + cu * 8 + (cc & 7)];
  }
  if (i < 512) slots[i] = 0u;   // re-armed every launch/replay
}

// ---------------- device helpers ----------------

__device__ __forceinline__ void ld1(bf16x8& dst, const short* ap) {
  asm volatile("global_load_dwordx4 %0, %1, off" : "=v"(dst) : "v"(ap));
}

// K-split h GEMM: NCH chunks from one base, groups of 8, depth-32 ring A[4][8],
// counted vmcnt. Plain cacheable loads (ring-freshness, R9/R10-proven).
template <int NCH, int G>
__device__ __forceinline__ void hgrp(f32x16* acc, bf16x8 (&A)[4][8], const short* pa,
                                     const short* __restrict__ pb) {
  if constexpr (G < NCH / 8) {
    constexpr int rem = NCH - 8 * (G + 1);
    constexpr int W = rem < 24 ? rem : 24;
    if constexpr (W == 24)      asm volatile("s_waitcnt vmcnt(24)" ::: "memory");
    else if constexpr (W == 16) asm volatile("s_waitcnt vmcnt(16)" ::: "memory");
    else if constexpr (W == 8)  asm volatile("s_waitcnt vmcnt(8)" ::: "memory");
    else                        asm volatile("s_waitcnt vmcnt(0)" ::: "memory");
#pragma unroll
    for (int j = 0; j < 8; ++j)
      asm volatile("" : "+v"(A[G & 3][j]));   // rule-18: pin MFMA below the wait
#pragma unroll
    for (int j = 0; j < 8; ++j) {
      bf16x8 b = *(const bf16x8*)(pb + (G * 8 + j) * 512);
      acc[j & 3] = __builtin_amdgcn_mfma_f32_32x32x16_bf16(A[G & 3][j], b, acc[j & 3], 0, 0, 0);
    }
    if constexpr (32 + 8 * G < NCH) {
#pragma unroll
      for (int j = 0; j < 8; ++j) ld1(A[G & 3][j], pa + (32 + 8 * G + j) * 512);
    }
    hgrp<NCH, G + 1>(acc, A, pa, pb);
  }
}

template <int NCH>
__device__ __forceinline__ void hgemm(f32x16* acc, const short* pa,
                                      const short* __restrict__ pb) {
  bf16x8 A[4][8];
#pragma unroll
  for (int g = 0; g < 4; ++g)
#pragma unroll
    for (int j = 0; j < 8; ++j) ld1(A[g][j], pa + (g * 8 + j) * 512);
  hgrp<NCH, 0>(acc, A, pa, pb);
}

// x GEMM from raw f32 x: 8 chunks, plain loads + in-register bf16 cvt
__device__ __forceinline__ void xgemm(f32x16* acc, const float* __restrict__ xlane,
                                      const short* __restrict__ pb) {
#pragma unroll
  for (int c = 0; c < 8; ++c) {
    float4 lo = *(const float4*)(xlane + c * 16);
    float4 hi = *(const float4*)(xlane + c * 16 + 4);
    bf16x8 a;
    a[0] = f2bf(lo.x); a[1] = f2bf(lo.y); a[2] = f2bf(lo.z); a[3] = f2bf(lo.w);
    a[4] = f2bf(hi.x); a[5] = f2bf(hi.y); a[6] = f2bf(hi.z); a[7] = f2bf(hi.w);
    bf16x8 b = *(const bf16x8*)(pb + c * 512);
    acc[c & 3] = __builtin_amdgcn_mfma_f32_32x32x16_bf16(a, b, acc[c & 3], 0, 0, 0);
  }
}

// ---------- persistent LSTM: 8 waves (2/SIMD), K-split pairs, wave0 flat poll ----------

__global__ void __launch_bounds__(512, 2) lstm_main(const float* __restrict__ x,
    short* __restrict__ h0r, short* __restrict__ h1r,
    const short* __restrict__ wp0, const short* __restrict__ wp1,
    const float* __restrict__ bpack, const float* __restrict__ cin,
    float* __restrict__ out, unsigned* __restrict__ slots) {
  __shared__ short wlds[128 * 512];   // 128 KB weights -> 1 block/CU
  __shared__ float4 aex[4][256];      // 16 KB K-split exchange, conflict-free layout
  __shared__ short hstage[4][256];    // 2 KB packed h staging (also feeds outs shadow)
  const int blk = blockIdx.x;
  const int layer = blk >> 7;
  const int cu = blk & 127;
  const int tid = threadIdx.x;
  const int lane = tid & 63;
  const int wave = tid >> 6;
  const int q = wave & 3;             // row-block (32 rows)
  const bool isB = wave >= 4;         // K-split upper half

  const int nkc = layer ? 128 : 72;
  const short* wsrc = layer ? (wp1 + (size_t)cu * 128 * 512) : (wp0 + (size_t)cu * 72 * 512);
  for (int i = tid; i < nkc * 64; i += 512)
    ((int4*)wlds)[i] = ((const int4*)wsrc)[i];
  __syncthreads();

  const int col = lane & 31;
  const float bias = bpack[layer * 4096 + cu * 32 + col];
  const int uu = col & 7;
  const bool ewlane = (col < 8);
  const int gcol = cu * 8 + uu;
  const int hi4 = (lane >> 5) << 2;
  const int koff = (lane >> 5) << 3;
  const size_t qsl = (size_t)q * 64 * 512 + lane * 8;               // row-block slice in entry
  const float* xl = x + (size_t)(q * 32 + col) * (TT * VV) + koff;  // L0 B-waves

  float creg[16];
  if (!isB) {
#pragma unroll
    for (int r = 0; r < 16; ++r) {
      int grow = q * 32 + (r & 3) + ((r >> 2) << 3) + hi4;
      creg[r] = ewlane ? cin[(size_t)layer * BB * HH + (size_t)grow * HH + gcol] : 0.f;
    }
  }

  f32x16 acc[4];
  if (!layer && isB) {   // prologue: x GEMM for t=0 (carried into phase 0's h-half)
#pragma unroll
    for (int r = 0; r < 16; ++r) { acc[0][r] = 0.f; acc[1][r] = 0.f; acc[2][r] = 0.f; acc[3][r] = 0.f; }
    xgemm(acc, xl, wlds + lane * 8);
  }

  for (int p = 0; p <= TT; ++p) {
    if (!layer && p == TT) break;

    // ---- wave0-only flat poll (1 L3 RTT), split targets ----
    if (wave == 0 && p > 0) {
      unsigned tgt;
      if (layer) tgt = (unsigned)p;                                   // L1: all >= p
      else tgt = (lane < 32) ? (unsigned)p                            // L0: own layer >= p,
                             : (p > 24 ? (unsigned)(p - 24) : 0u);    //     L1 >= p-24 (ring BP)
      const unsigned* p0 = slots + (lane << 2);
      for (;;) {
        u32x4 v;
        asm volatile("global_load_dwordx4 %0, %1, off sc0 sc1\n\ts_waitcnt vmcnt(0)"
                     : "=v"(v) : "v"(p0) : "memory");
        bool ok = (v[0] >= tgt) && (v[1] >= tgt) && (v[2] >= tgt) && (v[3] >= tgt);
        if (__all(ok)) break;
        __builtin_amdgcn_s_sleep(2);
      }
    }
    __syncthreads();   // S0: flags verified for everyone

    const bool active = layer ? (p >= 1) : true;
    const int t = layer ? (p - 1) : p;
    f32x16 ssum;

    if (active) {
      if (!isB) {
#pragma unroll
        for (int r = 0; r < 16; ++r) { acc[0][r] = bias; acc[1][r] = 0.f; acc[2][r] = 0.f; acc[3][r] = 0.f; }
      } else if (layer) {
#pragma unroll
        for (int r = 0; r < 16; ++r) { acc[0][r] = 0.f; acc[1][r] = 0.f; acc[2][r] = 0.f; acc[3][r] = 0.f; }
      }  // L0 B: acc carries x[t] partial from prologue/shadow

      if (!layer) {
        const short* he = h0r + (size_t)eidx(p - 1) * HPAR + qsl;
        if (!isB) hgemm<32>(acc, he, wlds + 8 * 512 + lane * 8);              // h k 0..511
        else      hgemm<32>(acc, he + 32 * 512, wlds + 40 * 512 + lane * 8);  // h k 512..1023
      } else {
        if (!isB) hgemm<64>(acc, h0r + (size_t)eidx(p - 1) * HPAR + qsl, wlds + lane * 8);
        else      hgemm<64>(acc, h1r + (size_t)eidx(p - 2) * HPAR + qsl, wlds + 64 * 512 + lane * 8);
      }
      ssum = (acc[0] + acc[1]) + (acc[2] + acc[3]);
      if (isB) {
#pragma unroll
        for (int j = 0; j < 4; ++j) {
          float4 v; v.x = ssum[4*j]; v.y = ssum[4*j+1]; v.z = ssum[4*j+2]; v.w = ssum[4*j+3];
          aex[q][j * 64 + lane] = v;
        }
      }
    }
    __syncthreads();   // S1: aex published

    if (active && !isB) {
      f32x16 accf = ssum;
#pragma unroll
      for (int j = 0; j < 4; ++j) {
        float4 v = aex[q][j * 64 + lane];
        accf[4*j] += v.x; accf[4*j+1] += v.y; accf[4*j+2] += v.z; accf[4*j+3] += v.w;
      }
#pragma unroll
      for (int r = 0; r < 16; ++r) {
        float a0 = accf[r];
        float nl = (col >= 16 && col < 24) ? ftanh(a0) : fsig(a0);
        float f_ = __shfl_xor(nl, 8);
        float g_ = __shfl_xor(nl, 16);
        float o_ = __shfl_xor(nl, 24);
        const int rloc = (r & 3) + ((r >> 2) << 3) + hi4;
        const int grow = q * 32 + rloc;
        if (ewlane) {
          float cnew = f_ * creg[r] + nl * g_;
          creg[r] = cnew;
          float hnew = o_ * ftanh(cnew);
          hstage[q][rloc * 8 + uu] = f2bf(hnew);
          if (t == TT - 1) {
            out[BTH + (size_t)layer * BB * HH + (size_t)grow * HH + gcol] = hnew;     // h_f
            out[BTH + (size_t)(2 + layer) * BB * HH + (size_t)grow * HH + gcol] = cnew; // c_f
          }
        }
      }
      if (p < TT) {
        short* hp = (layer ? h1r + (size_t)eidx(p - 1) * HPAR
                           : h0r + (size_t)eidx(p) * HPAR)
                    + ((size_t)q * 64 + (cu >> 1)) * 512 + ((cu & 1) << 8);
        if (lane < 32) {   // packed 512 B wave store, write-through to L3
          bf16x8 v = *(const bf16x8*)&hstage[q][lane * 8];
          asm volatile("global_store_dwordx4 %0, %1, off sc0 sc1"
                       :: "v"(hp + lane * 8), "v"(v) : "memory");
        }
        asm volatile("s_waitcnt vmcnt(0)" ::: "memory");   // h ack'd at L3 before flag
      }
    }
    __syncthreads();   // S2: all A-wave stores drained

    if (tid == 0)
      __hip_atomic_store(&slots[blk], (unsigned)(p + 1),
                         __ATOMIC_RELAXED, __HIP_MEMORY_SCOPE_AGENT);

    // ---- shadow work (after flag, off the inter-CU critical path) ----
    if (!layer) {
      if (isB && p + 1 < TT) {
#pragma unroll
        for (int r = 0; r < 16; ++r) { acc[0][r] = 0.f; acc[1][r] = 0.f; acc[2][r] = 0.f; acc[3][r] = 0.f; }
        xgemm(acc, xl + (size_t)(p + 1) * VV, wlds + lane * 8);
      }
    } else if (active && isB) {   // outs[b][t][:] from hstage (bf16->f32)
#pragma unroll
      for (int r = 0; r < 16; ++r) {
        const int rloc = (r & 3) + ((r >> 2) << 3) + hi4;
        const int grow = q * 32 + rloc;
        if (ewlane) {
          unsigned hb = (unsigned short)hstage[q][rloc * 8 + uu];
          out[(size_t)grow * TT * HH + (size_t)t * HH + gcol] = __uint_as_float(hb << 16);
        }
      }
    }

    if (p == TT) break;   // L1 final phase done
  }
}

// ---------------- host ----------------

extern "C" void kernel_launch(void* const* d_in, const int* in_sizes, int n_in,
                              void* d_out, int out_size, void* d_ws, size_t ws_size,
                              hipStream_t stream) {
  const float* x   = (const float*)d_in[0];
  const float* h   = (const float*)d_in[1];
  const float* c   = (const float*)d_in[2];
  const float* Wx0 = (const float*)d_in[3];
  const float* Wh0 = (const float*)d_in[4];
  const float* b0  = (const float*)d_in[5];
  const float* Wx1 = (const float*)d_in[6];
  const float* Wh1 = (const float*)d_in[7];
  const float* b1  = (const float*)d_in[8];
  float* out = (float*)d_out;

  char* ws = (char*)d_ws;
  short* wp0 = (short*)ws;                          //  9,437,184
  short* wp1 = (short*)(ws + 9437184);              // 16,777,216
  float* bp  = (float*)(ws + 26214400);             //     32,768
  unsigned* slots = (unsigned*)(ws + 26247168);     //      8,192
  short* h0r = (short*)(ws + 26255360);             //  8,388,608 (RING=32)
  short* h1r = (short*)(ws + 34643968);             //  8,388,608  -> 43,032,576 B total

  hipLaunchKernelGGL(init_state, dim3(512),  dim3(256), 0, stream, h, h0r, h1r);
  hipLaunchKernelGGL(pack_w,     dim3(4096), dim3(256), 0, stream, Wx0, Wh0, Wx1, Wh1, wp0, wp1);
  hipLaunchKernelGGL(pack_b,     dim3(32),   dim3(256), 0, stream, b0, b1, bp, slots);

  hipLaunchKernelGGL(lstm_main, dim3(256), dim3(512), 0, stream,
                     x, h0r, h1r, wp0, wp1, bp, c, out, slots);
}

// Round 13
// 6391.358 us; speedup vs baseline: 1.6441x; 1.6441x over previous
//
#include <hip/hip_runtime.h>

#define VV 128
#define HH 1024
#define BB 128
#define TT 512
#define G4 4096
#define BTH ((size_t)BB * TT * HH)
#define HPAR (4 * 64 * 512)   // shorts per h ring entry (256 KB)
#define RING 32

typedef __attribute__((ext_vector_type(8))) short bf16x8;
typedef __attribute__((ext_vector_type(16))) float f32x16;

__device__ __forceinline__ short f2bf(float f) {
  unsigned u = __float_as_uint(f);
  u = (u + 0x7fffu + ((u >> 16) & 1u)) >> 16;
  return (short)u;
}

__device__ __forceinline__ float fsig(float x) {
  x = fminf(fmaxf(x, -30.f), 30.f);
  float e = __expf(-x);
  return 1.f / (1.f + e);
}
__device__ __forceinline__ float ftanh(float x) {
  x = fminf(fmaxf(x, -15.f), 15.f);
  float e = __expf(-2.f * x);
  return (1.f - e) / (1.f + e);
}

__device__ __forceinline__ unsigned eidx(int t) {   // ring entry for h[t], scrambled
  return ((unsigned)(t + 1) * 37u) & (RING - 1);
}

// ---------------- pre-kernels ----------------

// h (L,B,H) -> fragment-stream ring entry 0 (the h[-1] slot, eidx(-1)=0)
__global__ void init_state(const float* __restrict__ h,
                           short* __restrict__ h0dst, short* __restrict__ h1dst) {
  const int n = 2 * HPAR;
  for (int i = blockIdx.x * blockDim.x + threadIdx.x; i < n; i += gridDim.x * blockDim.x) {
    int inner = i & (HPAR - 1);
    int l = i >> 17;
    int e = i & 7, lane = (i >> 3) & 63, kc = (i >> 9) & 63, rb = (i >> 15) & 3;
    int row = rb * 32 + (lane & 31);
    int j = kc * 16 + ((lane >> 5) << 3) + e;
    short hb = f2bf(h[((size_t)l * BB + row) * HH + j]);
    (l ? h1dst : h0dst)[inner] = hb;
  }
}

// Pack weights into per-CU per-kc per-lane MFMA B-fragment streams (bf16).
__global__ void pack_w(const float* __restrict__ Wx0, const float* __restrict__ Wh0,
                       const float* __restrict__ Wx1, const float* __restrict__ Wh1,
                       short* __restrict__ wp0, short* __restrict__ wp1) {
  const int n0 = 128 * 72 * 512;
  const int n1 = 128 * 128 * 512;
  for (int i = blockIdx.x * blockDim.x + threadIdx.x; i < n0 + n1; i += gridDim.x * blockDim.x) {
    if (i < n0) {
      int cu = i / (72 * 512);
      int rem = i - cu * (72 * 512);
      int kc = rem >> 9, le = rem & 511;
      int lane = le >> 3, e = le & 7;
      int k = kc * 16 + ((lane >> 5) << 3) + e;
      int cl = lane & 31;
      int gcol = (cl >> 3) * HH + cu * 8 + (cl & 7);
      float f = (k < VV) ? Wx0[(size_t)k * G4 + gcol] : Wh0[(size_t)(k - VV) * G4 + gcol];
      wp0[i] = f2bf(f);
    } else {
      int j = i - n0;
      int cu = j >> 16;
      int rem = j & 65535;
      int kc = rem >> 9, le = rem & 511;
      int lane = le >> 3, e = le & 7;
      int k = kc * 16 + ((lane >> 5) << 3) + e;
      int cl = lane & 31;
      int gcol = (cl >> 3) * HH + cu * 8 + (cl & 7);
      float f = (k < HH) ? Wx1[(size_t)k * G4 + gcol] : Wh1[(size_t)(k - HH) * G4 + gcol];
      wp1[j] = f2bf(f);
    }
  }
}

__global__ void pack_b(const float* __restrict__ b0, const float* __restrict__ b1,
                       float* __restrict__ bp, unsigned* __restrict__ slots) {
  int i = blockIdx.x * blockDim.x + threadIdx.x;
  if (i < 2 * 128 * 32) {
    int l = i >> 12;
    int cu = (i >> 5) & 127;
    int cc = i & 31;
    const float* b = l ? b1 : b0;
    bp[i] = b[(cc >> 3) * HH + cu * 8 + (cc & 7)];
  }
  if (i < 512) slots[i] = 0u;
}

// ---------------- persistent LSTM kernel ----------------

// Deep-pipelined h GEMM, plain cacheable loads (ring-freshness, R9/R10-proven).
template <int NCH>
__device__ __forceinline__ void hgemm(f32x16* acc, const short* pa0, const short* pa1,
                                      const short* __restrict__ pb) {
  constexpr int NG = NCH / 16;
  bf16x8 A[3][16];
#pragma unroll
  for (int g = 0; g < 3; ++g) {
#pragma unroll
    for (int j = 0; j < 16; ++j) {
      const int c = g * 16 + j;
      const short* ap = (c < 64) ? (pa0 + c * 512) : (pa1 + (c - 64) * 512);
      asm volatile("global_load_dwordx4 %0, %1, off" : "=v"(A[g][j]) : "v"(ap));
    }
  }
#pragma unroll
  for (int g = 0; g < NG; ++g) {
    const int rem = NG - 1 - g;
    if (rem >= 2)      asm volatile("s_waitcnt vmcnt(32)" ::: "memory");
    else if (rem == 1) asm volatile("s_waitcnt vmcnt(16)" ::: "memory");
    else               asm volatile("s_waitcnt vmcnt(0)" ::: "memory");
#pragma unroll
    for (int j = 0; j < 16; ++j)
      asm volatile("" : "+v"(A[g % 3][j]));      // rule-18: pin MFMA below the wait
#pragma unroll
    for (int j = 0; j < 16; ++j) {
      const int c = g * 16 + j;
      bf16x8 b = *(const bf16x8*)(pb + c * 512);
      acc[j & 3] = __builtin_amdgcn_mfma_f32_32x32x16_bf16(A[g % 3][j], b, acc[j & 3], 0, 0, 0);
    }
    if (g + 3 < NG) {
#pragma unroll
      for (int j = 0; j < 16; ++j) {
        const int c = (g + 3) * 16 + j;
        const short* ap = (c < 64) ? (pa0 + c * 512) : (pa1 + (c - 64) * 512);
        asm volatile("global_load_dwordx4 %0, %1, off"
                     : "=v"(A[(g + 3) % 3][j]) : "v"(ap));
      }
    }
  }
}

// x GEMM from raw f32 x: 8 chunks, plain cacheable loads + in-register bf16 cvt
__device__ __forceinline__ void xgemm_raw(f32x16* acc, const float* __restrict__ xlane,
                                          const short* __restrict__ pb) {
#pragma unroll
  for (int c = 0; c < 8; ++c) {
    float4 lo = *(const float4*)(xlane + c * 16);
    float4 hi = *(const float4*)(xlane + c * 16 + 4);
    bf16x8 a;
    a[0] = f2bf(lo.x); a[1] = f2bf(lo.y); a[2] = f2bf(lo.z); a[3] = f2bf(lo.w);
    a[4] = f2bf(hi.x); a[5] = f2bf(hi.y); a[6] = f2bf(hi.z); a[7] = f2bf(hi.w);
    bf16x8 b = *(const bf16x8*)(pb + c * 512);
    acc[c & 3] = __builtin_amdgcn_mfma_f32_32x32x16_bf16(a, b, acc[c & 3], 0, 0, 0);
  }
}

__global__ void __launch_bounds__(256, 1) lstm_main(const float* __restrict__ x,
    short* __restrict__ h0b, short* __restrict__ h1b,
    const short* __restrict__ wp0, const short* __restrict__ wp1,
    const float* __restrict__ bpack, const float* __restrict__ cin,
    float* __restrict__ out, unsigned* __restrict__ slots) {
  __shared__ short wlds[128 * 512];   // 128 KB weights
  __shared__ short hstage[4][256];    // 2 KB: packed h staging (one 512B slice per wave)
  unsigned* gdone = slots + 256;
  const int blk = blockIdx.x;
  const int layer = blk >> 7;
  const int cu = blk & 127;
  const int tid = threadIdx.x;
  const int lane = tid & 63;
  const int wave = tid >> 6;
  // Relay duty on L0 blocks only (they have ~2us slack vs L1's longer GEMM):
  // relay k = block k*16 (k=0..7, all layer-0), scans slots[k*32 .. k*32+31].
  const bool isRelay = ((blk & 15) == 0) && (blk < 128);
  const int rbase = (blk >> 4) << 5;    // k*32

  const int nkc = layer ? 128 : 72;
  const short* wsrc = layer ? (wp1 + (size_t)cu * 128 * 512) : (wp0 + (size_t)cu * 72 * 512);
  for (int i = tid; i < nkc * 64; i += 256)
    ((int4*)wlds)[i] = ((const int4*)wsrc)[i];
  __syncthreads();

  const int col = lane & 31;
  const float bias = bpack[layer * 4096 + cu * 32 + col];
  const int uu = col & 7;
  const bool ewlane = (col < 8);
  const int gcol = cu * 8 + uu;
  const int hi4 = ((lane >> 5) << 2);
  const int arow = wave * 32 + col;
  const int koff = (lane >> 5) << 3;
  const float* xlane0 = x + (size_t)arow * (TT * VV) + koff;   // + t*VV per phase

  float creg[16], hval[16];
#pragma unroll
  for (int r = 0; r < 16; ++r) {
    int grow = wave * 32 + (r & 3) + ((r >> 2) << 3) + hi4;
    creg[r] = ewlane ? cin[(size_t)layer * BB * HH + (size_t)grow * HH + gcol] : 0.f;
    hval[r] = 0.f;
  }

  const int pst = (wave * 64 + (cu >> 1)) * 512 + ((cu & 1) << 8);
  const int wv64 = wave * 64 * 512 + lane * 8;   // wave slice inside an entry

  f32x16 acc[4];
  auto initacc = [&]() {
#pragma unroll
    for (int r = 0; r < 16; ++r) {
      acc[0][r] = bias; acc[1][r] = 0.f; acc[2][r] = 0.f; acc[3][r] = 0.f;
    }
  };

  if (layer == 0) {   // prologue: x GEMM for t=0
    initacc();
    xgemm_raw(acc, xlane0, wlds + lane * 8);
  }

  for (int p = 0; p <= TT; ++p) {
    if (p > 0) {   // ---- hierarchical poll (relays on L0, sleep-free) ----
      const unsigned tgt = (unsigned)p;
      if (isRelay && tid < 32) {
        for (;;) {   // no sleep: relay latency is on everyone's critical path
          unsigned v = __hip_atomic_load(&slots[rbase + tid],
                                         __ATOMIC_RELAXED, __HIP_MEMORY_SCOPE_AGENT);
          if (__all(v >= tgt)) break;
        }
        if (tid == 0)
          __hip_atomic_store(&gdone[(blk >> 4) << 5], tgt,
                             __ATOMIC_RELAXED, __HIP_MEMORY_SCOPE_AGENT);
      }
      if (tid < 8) {
        for (;;) {
          unsigned v = __hip_atomic_load(&gdone[tid << 5],
                                         __ATOMIC_RELAXED, __HIP_MEMORY_SCOPE_AGENT);
          if (__all(v >= tgt)) break;
          __builtin_amdgcn_s_sleep(1);
        }
      }
      __syncthreads();
    }

    const bool active = layer ? (p >= 1) : (p < TT);
    const int t = layer ? (p - 1) : p;
    if (active) {
      const short* ra0 = h0b + (size_t)eidx(p - 1) * HPAR + wv64;  // h0[t-1] (L0) / h0[t] (L1)
      const short* ra1 = h1b + (size_t)eidx(p - 2) * HPAR + wv64;  // h1[t-1] (L1)
      if (layer == 0) {
        hgemm<64>(acc, ra0, ra0, wlds + 8 * 512 + lane * 8);
      } else {
        initacc();
        hgemm<128>(acc, ra0, ra1, wlds + lane * 8);
      }
      f32x16 accf = (acc[0] + acc[1]) + (acc[2] + acc[3]);
#pragma unroll
      for (int r = 0; r < 16; ++r) {
        float a0 = accf[r];
        float nl = (col >= 16 && col < 24) ? ftanh(a0) : fsig(a0);
        float f_ = __shfl_xor(nl, 8);
        float g_ = __shfl_xor(nl, 16);
        float o_ = __shfl_xor(nl, 24);
        const int rloc = (r & 3) + ((r >> 2) << 3) + hi4;
        const int grow = wave * 32 + rloc;
        float hnew = 0.f;
        if (ewlane) {
          float cnew = f_ * creg[r] + nl * g_;
          creg[r] = cnew;
          hnew = o_ * ftanh(cnew);
          hval[r] = hnew;
          hstage[wave][rloc * 8 + uu] = f2bf(hnew);   // pack for the wave store
          if (t == TT - 1) {
            out[BTH + (size_t)layer * BB * HH + (size_t)grow * HH + gcol] = hnew;          // h_f
            out[BTH + (size_t)(2 + layer) * BB * HH + (size_t)grow * HH + gcol] = creg[r]; // c_f
          }
        }
      }
      if (p < TT) {   // packed 512 B wave store of this CU's h slice, write-through to L3
        short* hp = (layer ? h1b + (size_t)eidx(p - 1) * HPAR
                           : h0b + (size_t)eidx(p) * HPAR) + pst;
        if (lane < 32) {
          bf16x8 v = *(const bf16x8*)&hstage[wave][lane * 8];
          asm volatile("global_store_dwordx4 %0, %1, off sc0 sc1"
                       :: "v"(hp + lane * 8), "v"(v) : "memory");
        }
        asm volatile("s_waitcnt vmcnt(0)" ::: "memory");   // h ack'd at L3 before flag
      }
    }

    if (p == TT) {
      if (layer && active && ewlane) {
#pragma unroll
        for (int r = 0; r < 16; ++r) {
          const int rloc = (r & 3) + ((r >> 2) << 3) + hi4;
          const int grow = wave * 32 + rloc;
          out[(size_t)grow * TT * HH + (size_t)t * HH + gcol] = hval[r];
        }
      }
      break;
    }

    __syncthreads();
    if (tid == 0)
      __hip_atomic_store(&slots[blk], (unsigned)(p + 1),
                         __ATOMIC_RELAXED, __HIP_MEMORY_SCOPE_AGENT);

    // ---- post-arrive overlap ----
    if (layer == 0) {
      if (p + 1 < TT) {
        initacc();
        xgemm_raw(acc, xlane0 + (size_t)(p + 1) * VV, wlds + lane * 8);
      }
    } else if (active && ewlane) {
#pragma unroll
      for (int r = 0; r < 16; ++r) {
        const int rloc = (r & 3) + ((r >> 2) << 3) + hi4;
        const int grow = wave * 32 + rloc;
        out[(size_t)grow * TT * HH + (size_t)t * HH + gcol] = hval[r];
      }
    }
  }
}

// ---------------- host ----------------

extern "C" void kernel_launch(void* const* d_in, const int* in_sizes, int n_in,
                              void* d_out, int out_size, void* d_ws, size_t ws_size,
                              hipStream_t stream) {
  const float* x   = (const float*)d_in[0];
  const float* h   = (const float*)d_in[1];
  const float* c   = (const float*)d_in[2];
  const float* Wx0 = (const float*)d_in[3];
  const float* Wh0 = (const float*)d_in[4];
  const float* b0  = (const float*)d_in[5];
  const float* Wx1 = (const float*)d_in[6];
  const float* Wh1 = (const float*)d_in[7];
  const float* b1  = (const float*)d_in[8];
  float* out = (float*)d_out;

  char* ws = (char*)d_ws;
  short* wp0 = (short*)ws;                          //  9,437,184
  short* wp1 = (short*)(ws + 9437184);              // 16,777,216
  float* bp  = (float*)(ws + 26214400);             //     32,768
  unsigned* slots = (unsigned*)(ws + 26247168);     //      2,048
  short* h0r = (short*)(ws + 26249216);             //  8,388,608 (RING=32)
  short* h1r = (short*)(ws + 34637824);             //  8,388,608  -> 43,026,432 B total

  hipLaunchKernelGGL(init_state, dim3(512),  dim3(256), 0, stream, h, h0r, h1r);
  hipLaunchKernelGGL(pack_w,     dim3(4096), dim3(256), 0, stream, Wx0, Wh0, Wx1, Wh1, wp0, wp1);
  hipLaunchKernelGGL(pack_b,     dim3(32),   dim3(256), 0, stream, b0, b1, bp, slots);

  hipLaunchKernelGGL(lstm_main, dim3(256), dim3(256), 0, stream,
                     x, h0r, h1r, wp0, wp1, bp, c, out, slots);
}